// Round 7
// baseline (166.096 us; speedup 1.0000x reference)
//
#include <hip/hip_runtime.h>

// out[b,c,d,h,w] = in[b,0,d, clamp(h+dy,0,H-1), clamp(w+dx,0,W-1)]
// (dy,dx): c0:(-1,-1) c1:(0,0) c2:(+1,+1) c3:(+1,-1) c4:(-1,+1)
// B=2, D=48, H=256, W=512 f32.
//
// R7: full-row waves. Each lane holds 8 floats/row (2 float4), so one wave
// spans W=512 exactly: per channel it writes a contiguous 16KB burst (vs
// R4's 1KB-at-2KB-stride), and BOTH w-halos come from intra-wave shuffles
// (zero divergent seam loads; W-edges clamp from own regs). NT stores kept
// (R6 A/B: plain stores regressed 53.5->65.2us). XCD swizzle: 96 consecutive
// logical blocks per XCD so h-adjacent blocks share halo rows in L2.

typedef float f32x4 __attribute__((ext_vector_type(4)));

constexpr int D = 48, H = 256, W = 512;
constexpr int HB = 8;          // output rows per wave
constexpr int WIN = HB + 2;    // window rows

__device__ __forceinline__ void nt_store(float* p, f32x4 v) {
    __builtin_nontemporal_store(v, reinterpret_cast<f32x4*>(p));
}

__global__ __launch_bounds__(256) void prop_kernel(
    const float* __restrict__ in, float* __restrict__ out) {
    const int lane = threadIdx.x & 63;
    const int wv   = threadIdx.x >> 6;         // 0..3: wave's h-subblock

    // XCD-aware swizzle: nwg=768, 8 XCDs, 96 logical blocks per XCD.
    // lb consecutive (halo-sharing h-neighbors) -> same XCD L2.
    int lb = (blockIdx.x & 7) * 96 + (blockIdx.x >> 3);
    const int h32 = lb & 7;                    // 8 h-blocks of 32 rows
    lb >>= 3;
    const int d = lb % D;
    const int b = lb / D;

    const int h0 = h32 * 32 + wv * HB;         // first output row of this wave
    const int w0 = lane * 8;                   // lane covers w0..w0+7

    const float* base = in + (b * D + d) * (H * W);

    // Load the (HB+2)-row window; 2 float4 per lane per row = full 2KB row/wave.
    f32x4 q0[WIN], q1[WIN];
    #pragma unroll
    for (int i = 0; i < WIN; ++i) {
        int r = h0 - 1 + i;
        r = r < 0 ? 0 : (r > H - 1 ? H - 1 : r);
        const float* row = base + r * W + w0;
        q0[i] = *reinterpret_cast<const f32x4*>(row);
        q1[i] = *reinterpret_cast<const f32x4*>(row + 4);
    }

    // w-halos purely intra-wave: L = row[w0-1] (lane-1's q1.w),
    // R = row[w0+8] (lane+1's q0.x); W-edges clamp from own registers.
    float L[WIN], R[WIN];
    #pragma unroll
    for (int i = 0; i < WIN; ++i) {
        float l  = __shfl_up(q1[i].w, 1);
        float rr = __shfl_down(q0[i].x, 1);
        L[i] = (lane == 0)  ? q0[i].x : l;
        R[i] = (lane == 63) ? q1[i].w : rr;
    }

    const int planeDHW = D * H * W;            // 6,291,456
    float* o0 = out + ((b * 5) * D + d) * (H * W) + h0 * W + w0;

    // Channel-major: per channel, HB full contiguous rows (16KB/wave burst).
    #pragma unroll
    for (int j = 0; j < HB; ++j) {             // c0: row h-1, w-1 shift
        const int m = j;
        f32x4 a = {L[m], q0[m].x, q0[m].y, q0[m].z};
        f32x4 c = {q0[m].w, q1[m].x, q1[m].y, q1[m].z};
        nt_store(o0 + j * W, a);
        nt_store(o0 + j * W + 4, c);
    }
    #pragma unroll
    for (int j = 0; j < HB; ++j) {             // c1: row h, no shift
        nt_store(o0 + planeDHW + j * W, q0[j + 1]);
        nt_store(o0 + planeDHW + j * W + 4, q1[j + 1]);
    }
    #pragma unroll
    for (int j = 0; j < HB; ++j) {             // c2: row h+1, w+1 shift
        const int p = j + 2;
        f32x4 a = {q0[p].y, q0[p].z, q0[p].w, q1[p].x};
        f32x4 c = {q1[p].y, q1[p].z, q1[p].w, R[p]};
        nt_store(o0 + 2 * planeDHW + j * W, a);
        nt_store(o0 + 2 * planeDHW + j * W + 4, c);
    }
    #pragma unroll
    for (int j = 0; j < HB; ++j) {             // c3: row h+1, w-1 shift
        const int p = j + 2;
        f32x4 a = {L[p], q0[p].x, q0[p].y, q0[p].z};
        f32x4 c = {q0[p].w, q1[p].x, q1[p].y, q1[p].z};
        nt_store(o0 + 3 * planeDHW + j * W, a);
        nt_store(o0 + 3 * planeDHW + j * W + 4, c);
    }
    #pragma unroll
    for (int j = 0; j < HB; ++j) {             // c4: row h-1, w+1 shift
        const int m = j;
        f32x4 a = {q0[m].y, q0[m].z, q0[m].w, q1[m].x};
        f32x4 c = {q1[m].y, q1[m].z, q1[m].w, R[m]};
        nt_store(o0 + 4 * planeDHW + j * W, a);
        nt_store(o0 + 4 * planeDHW + j * W + 4, c);
    }
}

extern "C" void kernel_launch(void* const* d_in, const int* in_sizes, int n_in,
                              void* d_out, int out_size, void* d_ws, size_t ws_size,
                              hipStream_t stream) {
    const float* in = (const float*)d_in[0];
    float* out = (float*)d_out;

    // grid: B * D * (H/32) = 2 * 48 * 8 = 768 blocks (4 waves x 8 rows each)
    const int grid = 2 * D * (H / 32);
    prop_kernel<<<grid, 256, 0, stream>>>(in, out);
}

// Round 8
// 55.288 us; speedup vs baseline: 3.0042x; 3.0042x over previous
//
#include <hip/hip_runtime.h>

// out[b,c,d,h,w] = in[b,0,d, clamp(h+dy,0,H-1), clamp(w+dx,0,W-1)]
// (dy,dx): c0:(-1,-1) c1:(0,0) c2:(+1,+1) c3:(+1,-1) c4:(-1,+1)
// B=2, D=48, H=256, W=512 f32.
//
// R8: full-row waves with PER-INSTRUCTION lane contiguity (R7 postmortem:
// lane-owns-8-consecutive-floats made every nt store write 16B at 32B
// stride -> 1.7x write amplification, 430MB vs 252MB). Lane now owns two
// HALF-ROW slots: q0 at w=4*lane (first 1KB), q1 at w=256+4*lane (second
// 1KB). Every store instruction is a contiguous 1KB wave burst; each row =
// 2KB contiguous; each channel = 16KB contiguous burst. Halos all
// intra-wave (half-seam via __shfl to lane 0/63). NT stores kept (R6 A/B).
// XCD swizzle kept (768 blocks, 96/XCD).

typedef float f32x4 __attribute__((ext_vector_type(4)));

constexpr int D = 48, H = 256, W = 512;
constexpr int HW2 = W / 2;     // 256: half-row
constexpr int HB = 8;          // output rows per wave
constexpr int WIN = HB + 2;    // window rows

__device__ __forceinline__ void nt_store(float* p, f32x4 v) {
    __builtin_nontemporal_store(v, reinterpret_cast<f32x4*>(p));
}

__global__ __launch_bounds__(256) void prop_kernel(
    const float* __restrict__ in, float* __restrict__ out) {
    const int lane = threadIdx.x & 63;
    const int wv   = threadIdx.x >> 6;         // 0..3: wave's h-subblock

    // XCD-aware swizzle: nwg=768 (%8==0), 96 consecutive logical blocks/XCD.
    int lb = (blockIdx.x & 7) * 96 + (blockIdx.x >> 3);
    const int h32 = lb & 7;                    // 8 h-blocks of 32 rows
    lb >>= 3;
    const int d = lb % D;
    const int b = lb / D;

    const int h0 = h32 * 32 + wv * HB;         // first output row of this wave
    const int w0 = lane * 4;                   // first-half slot w0..w0+3

    const float* base = in + (b * D + d) * (H * W);

    // Window rows [h0-1 .. h0+HB] clamped; per row two contiguous-1KB loads.
    f32x4 q0[WIN], q1[WIN];
    #pragma unroll
    for (int i = 0; i < WIN; ++i) {
        int r = h0 - 1 + i;
        r = r < 0 ? 0 : (r > H - 1 ? H - 1 : r);
        const float* row = base + r * W;
        q0[i] = *reinterpret_cast<const f32x4*>(row + w0);
        q1[i] = *reinterpret_cast<const f32x4*>(row + HW2 + w0);
    }

    // Halos, all intra-wave:
    //  L0 = row[w0-1]        : shfl_up(q0.w); lane 0 -> W-edge clamp (q0.x)
    //  R0 = row[w0+4]        : shfl_down(q0.x); lane 63 -> row[256] = lane0's q1.x
    //  L1 = row[256+w0-1]    : shfl_up(q1.w); lane 0 -> row[255] = lane63's q0.w
    //  R1 = row[256+w0+4]    : shfl_down(q1.x); lane 63 -> W-edge clamp (q1.w)
    float L0[WIN], R0[WIN], L1[WIN], R1[WIN];
    #pragma unroll
    for (int i = 0; i < WIN; ++i) {
        float l0 = __shfl_up(q0[i].w, 1);
        float r0 = __shfl_down(q0[i].x, 1);
        float l1 = __shfl_up(q1[i].w, 1);
        float r1 = __shfl_down(q1[i].x, 1);
        float seamA = __shfl(q1[i].x, 0);      // row[256] for lane 63
        float seamB = __shfl(q0[i].w, 63);     // row[255] for lane 0
        L0[i] = (lane == 0)  ? q0[i].x : l0;
        R0[i] = (lane == 63) ? seamA   : r0;
        L1[i] = (lane == 0)  ? seamB   : l1;
        R1[i] = (lane == 63) ? q1[i].w : r1;
    }

    const int planeDHW = D * H * W;            // 6,291,456
    float* o0 = out + ((b * 5) * D + d) * (H * W) + h0 * W + w0;

    // Channel-major; per row, both 1KB halves adjacent -> 2KB contiguous,
    // HB rows -> 16KB contiguous burst per channel per wave.
    #pragma unroll
    for (int j = 0; j < HB; ++j) {             // c0: row h-1, shift w-1
        const int m = j;
        f32x4 a = {L0[m], q0[m].x, q0[m].y, q0[m].z};
        f32x4 c = {L1[m], q1[m].x, q1[m].y, q1[m].z};
        nt_store(o0 + j * W, a);
        nt_store(o0 + j * W + HW2, c);
    }
    #pragma unroll
    for (int j = 0; j < HB; ++j) {             // c1: row h, no shift
        nt_store(o0 + planeDHW + j * W, q0[j + 1]);
        nt_store(o0 + planeDHW + j * W + HW2, q1[j + 1]);
    }
    #pragma unroll
    for (int j = 0; j < HB; ++j) {             // c2: row h+1, shift w+1
        const int p = j + 2;
        f32x4 a = {q0[p].y, q0[p].z, q0[p].w, R0[p]};
        f32x4 c = {q1[p].y, q1[p].z, q1[p].w, R1[p]};
        nt_store(o0 + 2 * planeDHW + j * W, a);
        nt_store(o0 + 2 * planeDHW + j * W + HW2, c);
    }
    #pragma unroll
    for (int j = 0; j < HB; ++j) {             // c3: row h+1, shift w-1
        const int p = j + 2;
        f32x4 a = {L0[p], q0[p].x, q0[p].y, q0[p].z};
        f32x4 c = {L1[p], q1[p].x, q1[p].y, q1[p].z};
        nt_store(o0 + 3 * planeDHW + j * W, a);
        nt_store(o0 + 3 * planeDHW + j * W + HW2, c);
    }
    #pragma unroll
    for (int j = 0; j < HB; ++j) {             // c4: row h-1, shift w+1
        const int m = j;
        f32x4 a = {q0[m].y, q0[m].z, q0[m].w, R0[m]};
        f32x4 c = {q1[m].y, q1[m].z, q1[m].w, R1[m]};
        nt_store(o0 + 4 * planeDHW + j * W, a);
        nt_store(o0 + 4 * planeDHW + j * W + HW2, c);
    }
}

extern "C" void kernel_launch(void* const* d_in, const int* in_sizes, int n_in,
                              void* d_out, int out_size, void* d_ws, size_t ws_size,
                              hipStream_t stream) {
    const float* in = (const float*)d_in[0];
    float* out = (float*)d_out;

    // grid: B * D * (H/32) = 2 * 48 * 8 = 768 blocks (4 waves x 8 rows each)
    const int grid = 2 * D * (H / 32);
    prop_kernel<<<grid, 256, 0, stream>>>(in, out);
}